// Round 1
// baseline (434.443 us; speedup 1.0000x reference)
//
#include <hip/hip_runtime.h>

#define LR 0.01f
#define EPS 1e-10f

// Inputs: idx (N, int32), grad (N,64 f32), state (V,64 f32), emb (V,64 f32)
// Outputs concatenated: new_state (V*64 f32) then new_emb (V*64 f32)
// Scratch: counts[V] int32 in d_ws (4 MB needed)

__global__ void zero_counts_kernel(int* __restrict__ counts, int V) {
    int i = blockIdx.x * blockDim.x + threadIdx.x;
    if (i < V) counts[i] = 0;
}

// One thread per 4 elements (16 threads per row). Zeroes the accumulator row
// (new_state region of d_out) and counts occurrences per vocab index.
__global__ void scatter_zero_count_kernel(const int* __restrict__ idx,
                                          float* __restrict__ accum,
                                          int* __restrict__ counts, int N) {
    int t = blockIdx.x * blockDim.x + threadIdx.x;
    int row = t >> 4;
    int q = t & 15;
    if (row >= N) return;
    int v = idx[row];
    float4* dst = reinterpret_cast<float4*>(accum + (size_t)v * 64 + q * 4);
    *dst = make_float4(0.f, 0.f, 0.f, 0.f);
    if (q == 0) atomicAdd(&counts[v], 1);
}

// Accumulate grad sums into accumulator (duplicates handled by atomics).
__global__ void scatter_add_kernel(const int* __restrict__ idx,
                                   const float* __restrict__ grad,
                                   float* __restrict__ accum, int N) {
    int t = blockIdx.x * blockDim.x + threadIdx.x;
    int row = t >> 4;
    int q = t & 15;
    if (row >= N) return;
    int v = idx[row];
    float4 g = *reinterpret_cast<const float4*>(grad + (size_t)row * 64 + q * 4);
    float* dst = accum + (size_t)v * 64 + q * 4;
    atomicAdd(dst + 0, g.x);
    atomicAdd(dst + 1, g.y);
    atomicAdd(dst + 2, g.z);
    atomicAdd(dst + 3, g.w);
}

// Full pass over V rows: untouched rows are plain copies; touched rows get
// the Adagrad update. Reads the accumulated grad sum from out_state (only on
// touched rows) and overwrites it with the new state.
__global__ void finalize_kernel(const float* __restrict__ state,
                                const float* __restrict__ emb,
                                const int* __restrict__ counts,
                                float* __restrict__ out_state,
                                float* __restrict__ out_emb, int V) {
    long long t = (long long)blockIdx.x * blockDim.x + threadIdx.x;  // over V*16
    long long row = t >> 4;
    int q = (int)(t & 15);
    if (row >= V) return;
    size_t off = (size_t)row * 64 + q * 4;
    int c = counts[row];
    float4 s = *reinterpret_cast<const float4*>(state + off);
    float4 e = *reinterpret_cast<const float4*>(emb + off);
    if (c > 0) {
        float4 a = *reinterpret_cast<const float4*>(out_state + off);
        float inv = 1.0f / (float)c;
        float m0 = a.x * inv, m1 = a.y * inv, m2 = a.z * inv, m3 = a.w * inv;
        float s0 = s.x + m0 * m0, s1 = s.y + m1 * m1;
        float s2 = s.z + m2 * m2, s3 = s.w + m3 * m3;
        float4 ns = make_float4(s0, s1, s2, s3);
        float4 ne = make_float4(e.x - LR * m0 / (sqrtf(s0) + EPS),
                                e.y - LR * m1 / (sqrtf(s1) + EPS),
                                e.z - LR * m2 / (sqrtf(s2) + EPS),
                                e.w - LR * m3 / (sqrtf(s3) + EPS));
        *reinterpret_cast<float4*>(out_state + off) = ns;
        *reinterpret_cast<float4*>(out_emb + off) = ne;
    } else {
        *reinterpret_cast<float4*>(out_state + off) = s;
        *reinterpret_cast<float4*>(out_emb + off) = e;
    }
}

extern "C" void kernel_launch(void* const* d_in, const int* in_sizes, int n_in,
                              void* d_out, int out_size, void* d_ws, size_t ws_size,
                              hipStream_t stream) {
    const int* idx = (const int*)d_in[0];
    const float* grad = (const float*)d_in[1];
    const float* state = (const float*)d_in[2];
    const float* emb = (const float*)d_in[3];

    int N = in_sizes[0];
    int D = in_sizes[1] / N;         // expected 64
    long long VD = in_sizes[2];
    int V = (int)(VD / D);

    float* out_state = (float*)d_out;
    float* out_emb = (float*)d_out + (size_t)V * D;
    int* counts = (int*)d_ws;        // V * 4 bytes

    // 1. zero counts
    {
        int threads = 256;
        int blocks = (V + threads - 1) / threads;
        zero_counts_kernel<<<blocks, threads, 0, stream>>>(counts, V);
    }
    // 2. scatter-zero accumulator rows + count
    {
        long long work = (long long)N * 16;
        int threads = 256;
        int blocks = (int)((work + threads - 1) / threads);
        scatter_zero_count_kernel<<<blocks, threads, 0, stream>>>(idx, out_state, counts, N);
    }
    // 3. scatter-add grads
    {
        long long work = (long long)N * 16;
        int threads = 256;
        int blocks = (int)((work + threads - 1) / threads);
        scatter_add_kernel<<<blocks, threads, 0, stream>>>(idx, grad, out_state, N);
    }
    // 4. finalize
    {
        long long work = (long long)V * 16;
        int threads = 256;
        int blocks = (int)((work + threads - 1) / threads);
        finalize_kernel<<<blocks, threads, 0, stream>>>(state, emb, counts,
                                                        out_state, out_emb, V);
    }
}

// Round 2
// 289.743 us; speedup vs baseline: 1.4994x; 1.4994x over previous
//
#include <hip/hip_runtime.h>

#define LR 0.01f
#define EPS 1e-10f

// Inputs: idx (N, int32), grad (N,64 f32), state (V,64 f32), emb (V,64 f32)
// Outputs concatenated: new_state (V*64 f32) then new_emb (V*64 f32)
// Scratch: counts[V] int32 in d_ws (4 MB needed)
//
// Strategy: most touched rows are unique (V >> N). Count first, then:
//   count==1 rows: plain vectorized copy of grad into the accumulator
//   count>1 rows:  write zeros (benign idempotent race), then atomic-add
//                  only the duplicate entries (~0.4% of elements).

__global__ void zero_counts_kernel(int* __restrict__ counts, int V) {
    int i = blockIdx.x * blockDim.x + threadIdx.x;
    if (i < V) counts[i] = 0;
}

// One thread per input row: count occurrences per vocab index.
__global__ void count_kernel(const int* __restrict__ idx,
                             int* __restrict__ counts, int N) {
    int i = blockIdx.x * blockDim.x + threadIdx.x;
    if (i >= N) return;
    atomicAdd(&counts[idx[i]], 1);
}

// 16 threads per input row. Unique rows: copy grad. Dup rows: zero.
__global__ void scatter_init_kernel(const int* __restrict__ idx,
                                    const float* __restrict__ grad,
                                    const int* __restrict__ counts,
                                    float* __restrict__ accum, int N) {
    int t = blockIdx.x * blockDim.x + threadIdx.x;
    int row = t >> 4;
    int q = t & 15;
    if (row >= N) return;
    int v = idx[row];
    int c = counts[v];
    float4 val;
    if (c == 1) {
        val = *reinterpret_cast<const float4*>(grad + (size_t)row * 64 + q * 4);
    } else {
        val = make_float4(0.f, 0.f, 0.f, 0.f);
    }
    *reinterpret_cast<float4*>(accum + (size_t)v * 64 + q * 4) = val;
}

// 16 threads per input row. Only duplicate entries do atomic adds.
__global__ void scatter_add_dup_kernel(const int* __restrict__ idx,
                                       const float* __restrict__ grad,
                                       const int* __restrict__ counts,
                                       float* __restrict__ accum, int N) {
    int t = blockIdx.x * blockDim.x + threadIdx.x;
    int row = t >> 4;
    int q = t & 15;
    if (row >= N) return;
    int v = idx[row];
    if (counts[v] <= 1) return;
    float4 g = *reinterpret_cast<const float4*>(grad + (size_t)row * 64 + q * 4);
    float* dst = accum + (size_t)v * 64 + q * 4;
    atomicAdd(dst + 0, g.x);
    atomicAdd(dst + 1, g.y);
    atomicAdd(dst + 2, g.z);
    atomicAdd(dst + 3, g.w);
}

// Full pass over V rows: untouched rows are plain copies; touched rows get
// the Adagrad update. Reads the accumulated grad sum from out_state (only on
// touched rows) and overwrites it with the new state.
__global__ void finalize_kernel(const float* __restrict__ state,
                                const float* __restrict__ emb,
                                const int* __restrict__ counts,
                                float* __restrict__ out_state,
                                float* __restrict__ out_emb, int V) {
    long long t = (long long)blockIdx.x * blockDim.x + threadIdx.x;  // over V*16
    long long row = t >> 4;
    int q = (int)(t & 15);
    if (row >= V) return;
    size_t off = (size_t)row * 64 + q * 4;
    int c = counts[row];
    float4 s = *reinterpret_cast<const float4*>(state + off);
    float4 e = *reinterpret_cast<const float4*>(emb + off);
    if (c > 0) {
        float4 a = *reinterpret_cast<const float4*>(out_state + off);
        float inv = 1.0f / (float)c;
        float m0 = a.x * inv, m1 = a.y * inv, m2 = a.z * inv, m3 = a.w * inv;
        float s0 = s.x + m0 * m0, s1 = s.y + m1 * m1;
        float s2 = s.z + m2 * m2, s3 = s.w + m3 * m3;
        float4 ns = make_float4(s0, s1, s2, s3);
        float4 ne = make_float4(e.x - LR * m0 / (sqrtf(s0) + EPS),
                                e.y - LR * m1 / (sqrtf(s1) + EPS),
                                e.z - LR * m2 / (sqrtf(s2) + EPS),
                                e.w - LR * m3 / (sqrtf(s3) + EPS));
        *reinterpret_cast<float4*>(out_state + off) = ns;
        *reinterpret_cast<float4*>(out_emb + off) = ne;
    } else {
        *reinterpret_cast<float4*>(out_state + off) = s;
        *reinterpret_cast<float4*>(out_emb + off) = e;
    }
}

extern "C" void kernel_launch(void* const* d_in, const int* in_sizes, int n_in,
                              void* d_out, int out_size, void* d_ws, size_t ws_size,
                              hipStream_t stream) {
    const int* idx = (const int*)d_in[0];
    const float* grad = (const float*)d_in[1];
    const float* state = (const float*)d_in[2];
    const float* emb = (const float*)d_in[3];

    int N = in_sizes[0];
    int D = in_sizes[1] / N;         // expected 64
    long long VD = in_sizes[2];
    int V = (int)(VD / D);

    float* out_state = (float*)d_out;
    float* out_emb = (float*)d_out + (size_t)V * D;
    int* counts = (int*)d_ws;        // V * 4 bytes

    const int threads = 256;

    // 1. zero counts
    zero_counts_kernel<<<(V + threads - 1) / threads, threads, 0, stream>>>(counts, V);

    // 2. count occurrences (scalar atomics on 4 MB L2-hot region)
    count_kernel<<<(N + threads - 1) / threads, threads, 0, stream>>>(idx, counts, N);

    // 3. init accumulator: copy (unique) or zero (dup)
    {
        long long work = (long long)N * 16;
        int blocks = (int)((work + threads - 1) / threads);
        scatter_init_kernel<<<blocks, threads, 0, stream>>>(idx, grad, counts, out_state, N);
    }
    // 4. atomic-add only duplicate entries
    {
        long long work = (long long)N * 16;
        int blocks = (int)((work + threads - 1) / threads);
        scatter_add_dup_kernel<<<blocks, threads, 0, stream>>>(idx, grad, counts, out_state, N);
    }
    // 5. finalize
    {
        long long work = (long long)V * 16;
        int blocks = (int)((work + threads - 1) / threads);
        finalize_kernel<<<blocks, threads, 0, stream>>>(state, emb, counts,
                                                        out_state, out_emb, V);
    }
}

// Round 3
// 214.419 us; speedup vs baseline: 2.0261x; 1.3513x over previous
//
#include <hip/hip_runtime.h>

#define LR 0.01f
#define EPS 1e-10f

// Inputs: idx (N, int32), grad (N,64 f32), state (V,64 f32), emb (V,64 f32)
// Outputs concatenated: new_state (V*64 f32) then new_emb (V*64 f32)
// Scratch: head[V] int32 (4 MB) + next[N] int32 (1 MB) in d_ws
//
// Strategy: build per-vocab-row linked lists of input rows (atomicExch only),
// then one fused streaming pass over V: untouched rows copy, touched rows
// gather their grad chain, compute mean, Adagrad-update. No float atomics,
// no accumulator round-trip; the only scattered traffic is the grad gather
// (64 MB, 87% of it effectively in-order since most chains have length 1).

__global__ void init_head_kernel(int* __restrict__ head, int V) {
    int i = blockIdx.x * blockDim.x + threadIdx.x;
    if (i < V) head[i] = -1;
}

__global__ void link_kernel(const int* __restrict__ idx,
                            int* __restrict__ head,
                            int* __restrict__ next, int N) {
    int i = blockIdx.x * blockDim.x + threadIdx.x;
    if (i >= N) return;
    next[i] = atomicExch(&head[idx[i]], i);
}

// 16 threads per vocab row (each handles one float4 of the 64-wide row).
__global__ void fused_kernel(const float* __restrict__ state,
                             const float* __restrict__ emb,
                             const float* __restrict__ grad,
                             const int* __restrict__ head,
                             const int* __restrict__ next,
                             float* __restrict__ out_state,
                             float* __restrict__ out_emb, int V) {
    long long t = (long long)blockIdx.x * blockDim.x + threadIdx.x;  // V*16
    long long row = t >> 4;
    int q = (int)(t & 15);
    if (row >= V) return;
    size_t off = (size_t)row * 64 + (size_t)q * 4;

    int h = head[row];
    float4 s = *reinterpret_cast<const float4*>(state + off);
    float4 e = *reinterpret_cast<const float4*>(emb + off);

    if (h < 0) {
        // untouched: plain copy
        *reinterpret_cast<float4*>(out_state + off) = s;
        *reinterpret_cast<float4*>(out_emb + off) = e;
        return;
    }

    // touched: gather grad rows along the chain
    float sum0 = 0.f, sum1 = 0.f, sum2 = 0.f, sum3 = 0.f;
    int c = 0;
    for (int j = h; j >= 0; j = next[j]) {
        const float4 g = *reinterpret_cast<const float4*>(grad + (size_t)j * 64 + (size_t)q * 4);
        sum0 += g.x; sum1 += g.y; sum2 += g.z; sum3 += g.w;
        ++c;
    }
    float inv = 1.0f / (float)c;
    float m0 = sum0 * inv, m1 = sum1 * inv, m2 = sum2 * inv, m3 = sum3 * inv;
    float s0 = s.x + m0 * m0, s1 = s.y + m1 * m1;
    float s2 = s.z + m2 * m2, s3 = s.w + m3 * m3;
    float4 ns = make_float4(s0, s1, s2, s3);
    float4 ne = make_float4(e.x - LR * m0 / (sqrtf(s0) + EPS),
                            e.y - LR * m1 / (sqrtf(s1) + EPS),
                            e.z - LR * m2 / (sqrtf(s2) + EPS),
                            e.w - LR * m3 / (sqrtf(s3) + EPS));
    *reinterpret_cast<float4*>(out_state + off) = ns;
    *reinterpret_cast<float4*>(out_emb + off) = ne;
}

extern "C" void kernel_launch(void* const* d_in, const int* in_sizes, int n_in,
                              void* d_out, int out_size, void* d_ws, size_t ws_size,
                              hipStream_t stream) {
    const int* idx = (const int*)d_in[0];
    const float* grad = (const float*)d_in[1];
    const float* state = (const float*)d_in[2];
    const float* emb = (const float*)d_in[3];

    int N = in_sizes[0];
    int D = in_sizes[1] / N;         // expected 64
    long long VD = in_sizes[2];
    int V = (int)(VD / D);

    float* out_state = (float*)d_out;
    float* out_emb = (float*)d_out + (size_t)V * D;
    int* head = (int*)d_ws;                    // V ints
    int* next = (int*)d_ws + V;                // N ints

    const int threads = 256;

    // 1. head = -1
    init_head_kernel<<<(V + threads - 1) / threads, threads, 0, stream>>>(head, V);

    // 2. build chains (int atomics on 4 MB L2-hot region)
    link_kernel<<<(N + threads - 1) / threads, threads, 0, stream>>>(idx, head, next, N);

    // 3. fused streaming pass: copy or gather+update, write both outputs
    {
        long long work = (long long)V * 16;
        int blocks = (int)((work + threads - 1) / threads);
        fused_kernel<<<blocks, threads, 0, stream>>>(state, emb, grad, head, next,
                                                     out_state, out_emb, V);
    }
}